// Round 5
// baseline (2775.831 us; speedup 1.0000x reference)
//
#include <hip/hip_runtime.h>

// NGCF forward on gfx950 — round 5: R4 CSR structure + bf16 feature table
// for the SpMM gather (halves the dominant random-gather traffic).
// fp32 accumulate, fp32 transform/output; only the gathered neighbor
// features are rounded to bf16 (RNE), once per layer.

#define EMB 64

constexpr int kNUsers = 100000;
constexpr int kNItems = 50000;
constexpr int kNNodes = 150000;
constexpr int kNEdges = 4800000;
constexpr int kBatch  = 16384;
constexpr int kLayers = 3;
constexpr int kScanB  = (kNNodes + 255) / 256;   // 586 scan blocks
constexpr int kEPW    = 16;                      // fallback only

__device__ __forceinline__ float f4c(const float4& v, int i) {
  return ((const float*)&v)[i];
}
__device__ __forceinline__ float4 f4fma(float s, float4 w, float4 a) {
  a.x = fmaf(s, w.x, a.x);
  a.y = fmaf(s, w.y, a.y);
  a.z = fmaf(s, w.z, a.z);
  a.w = fmaf(s, w.w, a.w);
  return a;
}
__device__ __forceinline__ float lrelu(float x) { return x > 0.f ? x : 0.2f * x; }
__device__ __forceinline__ unsigned short f2bf(float f) {   // RNE
  unsigned int u = __float_as_uint(f);
  u = (u + 0x7fffu + ((u >> 16) & 1u)) >> 16;
  return (unsigned short)u;
}
__device__ __forceinline__ float bf2f(unsigned short h) {
  return __uint_as_float(((unsigned int)h) << 16);
}

// ---------------------------------------------------------------------------
// init: cur = concat(user_emb, item_emb); cur16 = bf16(cur).  float4 grain.
// ---------------------------------------------------------------------------
__global__ __launch_bounds__(256) void init_embed(
    const float* __restrict__ user_emb, const float* __restrict__ item_emb,
    float* __restrict__ cur, unsigned short* __restrict__ cur16, int with16)
{
  const size_t userF = (size_t)kNUsers * EMB;
  const size_t allF4 = (size_t)kNNodes * EMB / 4;
  const size_t i = (size_t)blockIdx.x * 256 + threadIdx.x;
  if (i >= allF4) return;
  const size_t f = i * 4;
  const float4 v = (f < userF) ? ((const float4*)user_emb)[i]
                               : ((const float4*)(item_emb))[(f - userF) / 4];
  ((float4*)cur)[i] = v;
  if (with16) {
    ushort4 h;
    h.x = f2bf(v.x); h.y = f2bf(v.y); h.z = f2bf(v.z); h.w = f2bf(v.w);
    ((ushort4*)cur16)[i] = h;
  }
}

// ---------------------------------------------------------------------------
// CSR build (unchanged from R4)
// ---------------------------------------------------------------------------
__global__ __launch_bounds__(256) void hist_rows(
    const int* __restrict__ rows, int* __restrict__ rowCnt)
{
  const int e = blockIdx.x * 256 + threadIdx.x;
  if (e < kNEdges) atomicAdd(&rowCnt[rows[e]], 1);
}

__global__ __launch_bounds__(256) void scan1(
    int* __restrict__ rowCnt, int* __restrict__ rowPtr,
    int* __restrict__ blockSums)
{
  __shared__ int wsum[4];
  const int tid  = threadIdx.x;
  const int lane = tid & 63;
  const int wid  = tid >> 6;
  const int i    = blockIdx.x * 256 + tid;
  const int cnt  = (i < kNNodes) ? rowCnt[i] : 0;
  int v = cnt;
#pragma unroll
  for (int off = 1; off < 64; off <<= 1) {
    const int n = __shfl_up(v, off, 64);
    if (lane >= off) v += n;
  }
  if (lane == 63) wsum[wid] = v;
  __syncthreads();
  if (tid == 0) {
    int s = 0;
#pragma unroll
    for (int w = 0; w < 4; ++w) { const int t = wsum[w]; wsum[w] = s; s += t; }
    blockSums[blockIdx.x] = s;
  }
  __syncthreads();
  if (i < kNNodes) {
    rowPtr[i] = wsum[wid] + v - cnt;
    rowCnt[i] = 0;
  }
}

__global__ __launch_bounds__(1024) void scan2(int* __restrict__ blockSums)
{
  __shared__ int wsum[16];
  const int tid  = threadIdx.x;
  const int lane = tid & 63;
  const int wid  = tid >> 6;
  const int cnt  = (tid < kScanB) ? blockSums[tid] : 0;
  int v = cnt;
#pragma unroll
  for (int off = 1; off < 64; off <<= 1) {
    const int n = __shfl_up(v, off, 64);
    if (lane >= off) v += n;
  }
  if (lane == 63) wsum[wid] = v;
  __syncthreads();
  if (tid == 0) {
    int s = 0;
#pragma unroll
    for (int w = 0; w < 16; ++w) { const int t = wsum[w]; wsum[w] = s; s += t; }
  }
  __syncthreads();
  if (tid < kScanB) blockSums[tid] = wsum[wid] + v - cnt;
}

__global__ __launch_bounds__(256) void scan3(
    int* __restrict__ rowPtr, const int* __restrict__ blockSums)
{
  const int i = blockIdx.x * 256 + threadIdx.x;
  if (i < kNNodes) rowPtr[i] += blockSums[blockIdx.x];
  if (i == 0) rowPtr[kNNodes] = kNEdges;
}

__global__ __launch_bounds__(256) void scatter_edges(
    const int* __restrict__ rows, const int* __restrict__ cols,
    const float* __restrict__ vals, const int* __restrict__ rowPtr,
    int* __restrict__ rowCnt, int2* __restrict__ edgeS)
{
  const int e = blockIdx.x * 256 + threadIdx.x;
  if (e >= kNEdges) return;
  const int r   = rows[e];
  const int idx = rowPtr[r] + atomicAdd(&rowCnt[r], 1);
  edgeS[idx] = make_int2(cols[e], __float_as_int(vals[e]));
}

// ---------------------------------------------------------------------------
// CSR SpMM, bf16 gather: one wave per row, lane = dim; 128 B/edge gather.
// ---------------------------------------------------------------------------
__global__ __launch_bounds__(256) void spmm_csr16(
    const unsigned short* __restrict__ cur16, const int* __restrict__ rowPtr,
    const int2* __restrict__ edgeS, float* __restrict__ nbuf)
{
  const int lane = threadIdx.x & 63;
  const int r = (blockIdx.x << 2) | (threadIdx.x >> 6);
  if (r >= kNNodes) return;
  const int start = __builtin_amdgcn_readfirstlane(rowPtr[r]);
  const int end   = __builtin_amdgcn_readfirstlane(rowPtr[r + 1]);
  float a0 = 0.f, a1 = 0.f, a2 = 0.f, a3 = 0.f;
  int e = start;
  for (; e + 4 <= end; e += 4) {
    const int2 cv0 = edgeS[e];
    const int2 cv1 = edgeS[e + 1];
    const int2 cv2 = edgeS[e + 2];
    const int2 cv3 = edgeS[e + 3];
    const unsigned short u0 = cur16[(size_t)cv0.x * EMB + lane];
    const unsigned short u1 = cur16[(size_t)cv1.x * EMB + lane];
    const unsigned short u2 = cur16[(size_t)cv2.x * EMB + lane];
    const unsigned short u3 = cur16[(size_t)cv3.x * EMB + lane];
    a0 = fmaf(__int_as_float(cv0.y), bf2f(u0), a0);
    a1 = fmaf(__int_as_float(cv1.y), bf2f(u1), a1);
    a2 = fmaf(__int_as_float(cv2.y), bf2f(u2), a2);
    a3 = fmaf(__int_as_float(cv3.y), bf2f(u3), a3);
  }
  for (; e < end; ++e) {
    const int2 cv = edgeS[e];
    a0 = fmaf(__int_as_float(cv.y), bf2f(cur16[(size_t)cv.x * EMB + lane]), a0);
  }
  nbuf[(size_t)r * EMB + lane] = (a0 + a1) + (a2 + a3);
}

// fp32-gather variant (fallback when ws can't hold cur16)
__global__ __launch_bounds__(256) void spmm_csr(
    const float* __restrict__ cur, const int* __restrict__ rowPtr,
    const int2* __restrict__ edgeS, float* __restrict__ nbuf)
{
  const int lane = threadIdx.x & 63;
  const int r = (blockIdx.x << 2) | (threadIdx.x >> 6);
  if (r >= kNNodes) return;
  const int start = __builtin_amdgcn_readfirstlane(rowPtr[r]);
  const int end   = __builtin_amdgcn_readfirstlane(rowPtr[r + 1]);
  float a0 = 0.f, a1 = 0.f, a2 = 0.f, a3 = 0.f;
  int e = start;
  for (; e + 4 <= end; e += 4) {
    const int2 cv0 = edgeS[e];
    const int2 cv1 = edgeS[e + 1];
    const int2 cv2 = edgeS[e + 2];
    const int2 cv3 = edgeS[e + 3];
    a0 = fmaf(__int_as_float(cv0.y), cur[(size_t)cv0.x * EMB + lane], a0);
    a1 = fmaf(__int_as_float(cv1.y), cur[(size_t)cv1.x * EMB + lane], a1);
    a2 = fmaf(__int_as_float(cv2.y), cur[(size_t)cv2.x * EMB + lane], a2);
    a3 = fmaf(__int_as_float(cv3.y), cur[(size_t)cv3.x * EMB + lane], a3);
  }
  for (; e < end; ++e) {
    const int2 cv = edgeS[e];
    a0 = fmaf(__int_as_float(cv.y), cur[(size_t)cv.x * EMB + lane], a0);
  }
  nbuf[(size_t)r * EMB + lane] = (a0 + a1) + (a2 + a3);
}

__global__ __launch_bounds__(256) void spmm_atomic(
    const float* __restrict__ cur, const int* __restrict__ rows,
    const int* __restrict__ cols, const float* __restrict__ vals,
    float* __restrict__ nbuf)
{
  const int lane = threadIdx.x & 63;
  int wv = (blockIdx.x << 2) | (threadIdx.x >> 6);
  wv = __builtin_amdgcn_readfirstlane(wv);
  int e0 = wv * kEPW;
  int e1 = e0 + kEPW;
  if (e1 > kNEdges) e1 = kNEdges;
  for (int e = e0; e < e1; ++e) {
    atomicAdd(nbuf + (size_t)rows[e] * EMB + lane,
              vals[e] * cur[(size_t)cols[e] * EMB + lane]);
  }
}

// ---------------------------------------------------------------------------
// Fused per-node transform; also refreshes the bf16 shadow when cur16 != 0.
// ---------------------------------------------------------------------------
__global__ __launch_bounds__(256) void transform_inplace(
    float* __restrict__ cur, const float* __restrict__ nbuf,
    const float* __restrict__ W1, const float* __restrict__ b1,
    const float* __restrict__ W2, const float* __restrict__ b2,
    unsigned short* __restrict__ cur16)
{
  const int node = blockIdx.x * 256 + threadIdx.x;
  if (node >= kNNodes) return;

  const float4* __restrict__ xr  = (const float4*)(cur  + (size_t)node * EMB);
  const float4* __restrict__ nr  = (const float4*)(nbuf + (size_t)node * EMB);
  const float4* __restrict__ b1v = (const float4*)b1;
  const float4* __restrict__ b2v = (const float4*)b2;

  float4 acc1[16], acc2[16];
#pragma unroll
  for (int j = 0; j < 16; ++j) { acc1[j] = b1v[j]; acc2[j] = b2v[j]; }

#pragma unroll 2
  for (int k4 = 0; k4 < 16; ++k4) {
    const float4 xv = xr[k4];
    const float4 nv = nr[k4];
#pragma unroll
    for (int kk = 0; kk < 4; ++kk) {
      const int k = 4 * k4 + kk;
      const float xs = f4c(xv, kk);
      const float ns = f4c(nv, kk);
      const float4* __restrict__ w1r = (const float4*)(W1 + k * EMB);
      const float4* __restrict__ w2r = (const float4*)(W2 + k * EMB);
#pragma unroll
      for (int j = 0; j < 16; ++j) {
        acc1[j] = f4fma(xs, w1r[j], acc1[j]);
        acc2[j] = f4fma(ns, w2r[j], acc2[j]);
      }
    }
  }

#pragma unroll
  for (int k4 = 0; k4 < 16; ++k4) {
    const float4 xv = xr[k4];
    const float4 tv = acc2[k4];
#pragma unroll
    for (int kk = 0; kk < 4; ++kk) {
      const float ms = f4c(tv, kk) * f4c(xv, kk);
      const float4* __restrict__ w2r = (const float4*)(W2 + (4 * k4 + kk) * EMB);
#pragma unroll
      for (int j = 0; j < 16; ++j) acc1[j] = f4fma(ms, w2r[j], acc1[j]);
    }
  }

  float4*  __restrict__ outp = (float4*)(cur + (size_t)node * EMB);
  ushort4* __restrict__ out16 = cur16 ? (ushort4*)(cur16 + (size_t)node * EMB)
                                      : (ushort4*)nullptr;
#pragma unroll
  for (int j = 0; j < 16; ++j) {
    float4 r;
    r.x = lrelu(acc1[j].x + acc2[j].x + b2v[j].x);
    r.y = lrelu(acc1[j].y + acc2[j].y + b2v[j].y);
    r.z = lrelu(acc1[j].z + acc2[j].z + b2v[j].z);
    r.w = lrelu(acc1[j].w + acc2[j].w + b2v[j].w);
    outp[j] = r;
    if (out16) {
      ushort4 h;
      h.x = f2bf(r.x); h.y = f2bf(r.y); h.z = f2bf(r.z); h.w = f2bf(r.w);
      out16[j] = h;
    }
  }
}

// ---------------------------------------------------------------------------
__global__ __launch_bounds__(256) void gather_out(
    const float* __restrict__ cur, const int* __restrict__ users,
    const int* __restrict__ pos, const int* __restrict__ neg,
    float* __restrict__ out, int layer)
{
  const int t    = blockIdx.x * 256 + threadIdx.x;
  const int lane = t & 63;
  const int rid  = t >> 6;
  if (rid >= 3 * kBatch) return;
  const int seg = rid / kBatch;
  const int b   = rid - seg * kBatch;
  int idx;
  if (seg == 0)      idx = users[b];
  else if (seg == 1) idx = pos[b] + kNUsers;
  else               idx = neg[b] + kNUsers;
  out[(size_t)rid * 256 + layer * EMB + lane] = cur[(size_t)idx * EMB + lane];
}

// ---------------------------------------------------------------------------
extern "C" void kernel_launch(void* const* d_in, const int* in_sizes, int n_in,
                              void* d_out, int out_size, void* d_ws, size_t ws_size,
                              hipStream_t stream) {
  const int*   users    = (const int*)d_in[0];
  const int*   pos      = (const int*)d_in[1];
  const int*   neg      = (const int*)d_in[2];
  const int*   rows     = (const int*)d_in[3];
  const int*   cols     = (const int*)d_in[4];
  const float* vals     = (const float*)d_in[5];
  const float* user_emb = (const float*)d_in[6];
  const float* item_emb = (const float*)d_in[7];
  const float* W1s      = (const float*)d_in[8];
  const float* b1s      = (const float*)d_in[9];
  const float* W2s      = (const float*)d_in[10];
  const float* b2s      = (const float*)d_in[11];
  float* out = (float*)d_out;

  const size_t nodeF = (size_t)kNNodes * EMB;
  float* cur  = (float*)d_ws;                               // 38.4 MB
  float* nbuf = cur + nodeF;                                // 38.4 MB
  int2*  edgeS     = (int2*)(nbuf + nodeF);                 // 38.4 MB
  int*   rowPtr    = (int*)(edgeS + kNEdges);               // 600 KB (+1)
  int*   rowCnt    = rowPtr + (kNNodes + 1);                // 600 KB
  int*   blockSums = rowCnt + kNNodes;                      // 2.3 KB
  unsigned short* cur16 = (unsigned short*)(blockSums + kScanB);  // 19.2 MB
  const size_t neededCsr = (size_t)((char*)cur16 - (char*)d_ws);
  const size_t needed16  = neededCsr + nodeF * sizeof(unsigned short);
  const bool useCsr = ws_size >= neededCsr;
  const bool use16  = ws_size >= needed16;
  unsigned short* c16 = use16 ? cur16 : nullptr;

  const dim3 blk(256);
  const int iblocks = (int)((nodeF / 4 + 255) / 256);       // 9375
  const int gblocks = (3 * kBatch * EMB + 255) / 256;       // 12288
  const int eblocks = (kNEdges + 255) / 256;                // 18750
  const int rblocks = (kNNodes + 3) / 4;                    // 37500
  const int tblocks = (kNNodes + 255) / 256;                // 586

  init_embed<<<iblocks, blk, 0, stream>>>(user_emb, item_emb, cur, cur16,
                                          use16 ? 1 : 0);

  if (useCsr) {
    hipMemsetAsync(rowCnt, 0, (size_t)kNNodes * sizeof(int), stream);
    hist_rows<<<eblocks, blk, 0, stream>>>(rows, rowCnt);
    scan1<<<kScanB, blk, 0, stream>>>(rowCnt, rowPtr, blockSums);
    scan2<<<1, 1024, 0, stream>>>(blockSums);
    scan3<<<kScanB, blk, 0, stream>>>(rowPtr, blockSums);
    scatter_edges<<<eblocks, blk, 0, stream>>>(rows, cols, vals, rowPtr,
                                               rowCnt, edgeS);
  }

  gather_out<<<gblocks, blk, 0, stream>>>(cur, users, pos, neg, out, 0);

  for (int L = 0; L < kLayers; ++L) {
    if (useCsr) {
      if (use16)
        spmm_csr16<<<rblocks, blk, 0, stream>>>(cur16, rowPtr, edgeS, nbuf);
      else
        spmm_csr<<<rblocks, blk, 0, stream>>>(cur, rowPtr, edgeS, nbuf);
    } else {
      hipMemsetAsync(nbuf, 0, nodeF * sizeof(float), stream);
      const int sblocks = (((kNEdges + kEPW - 1) / kEPW) + 3) / 4;
      spmm_atomic<<<sblocks, blk, 0, stream>>>(cur, rows, cols, vals, nbuf);
    }
    transform_inplace<<<tblocks, blk, 0, stream>>>(
        cur, nbuf, W1s + L * EMB * EMB, b1s + L * EMB,
        W2s + L * EMB * EMB, b2s + L * EMB, c16);
    gather_out<<<gblocks, blk, 0, stream>>>(cur, users, pos, neg, out, L + 1);
  }
}

// Round 6
// 1625.807 us; speedup vs baseline: 1.7074x; 1.7074x over previous
//
#include <hip/hip_runtime.h>

// NGCF forward on gfx950 — round 6: R4 CSR + bf16-gather SpMM, with the
// bf16 shadow refresh in its OWN streaming kernel (R5 fused it into the
// transform epilogue and tanked VALUBusy 100->25%).

#define EMB 64

constexpr int kNUsers = 100000;
constexpr int kNItems = 50000;
constexpr int kNNodes = 150000;
constexpr int kNEdges = 4800000;
constexpr int kBatch  = 16384;
constexpr int kLayers = 3;
constexpr int kScanB  = (kNNodes + 255) / 256;   // 586 scan blocks
constexpr int kEPW    = 16;                      // fallback only

__device__ __forceinline__ float f4c(const float4& v, int i) {
  return ((const float*)&v)[i];
}
__device__ __forceinline__ float4 f4fma(float s, float4 w, float4 a) {
  a.x = fmaf(s, w.x, a.x);
  a.y = fmaf(s, w.y, a.y);
  a.z = fmaf(s, w.z, a.z);
  a.w = fmaf(s, w.w, a.w);
  return a;
}
__device__ __forceinline__ float lrelu(float x) { return x > 0.f ? x : 0.2f * x; }
__device__ __forceinline__ unsigned short f2bf(float f) {   // RNE
  unsigned int u = __float_as_uint(f);
  u = (u + 0x7fffu + ((u >> 16) & 1u)) >> 16;
  return (unsigned short)u;
}
__device__ __forceinline__ float bf2f(unsigned short h) {
  return __uint_as_float(((unsigned int)h) << 16);
}

// ---------------------------------------------------------------------------
// init: cur = concat(user_emb, item_emb); cur16 = bf16(cur).
// ---------------------------------------------------------------------------
__global__ __launch_bounds__(256) void init_embed(
    const float* __restrict__ user_emb, const float* __restrict__ item_emb,
    float* __restrict__ cur, unsigned short* __restrict__ cur16, int with16)
{
  const size_t userF = (size_t)kNUsers * EMB;
  const size_t allF4 = (size_t)kNNodes * EMB / 4;
  const size_t i = (size_t)blockIdx.x * 256 + threadIdx.x;
  if (i >= allF4) return;
  const size_t f = i * 4;
  const float4 v = (f < userF) ? ((const float4*)user_emb)[i]
                               : ((const float4*)(item_emb))[(f - userF) / 4];
  ((float4*)cur)[i] = v;
  if (with16) {
    ushort4 h;
    h.x = f2bf(v.x); h.y = f2bf(v.y); h.z = f2bf(v.z); h.w = f2bf(v.w);
    ((ushort4*)cur16)[i] = h;
  }
}

// Streaming bf16 shadow refresh: cur16 = bf16(cur).
__global__ __launch_bounds__(256) void refresh16(
    const float* __restrict__ cur, unsigned short* __restrict__ cur16)
{
  const size_t allF4 = (size_t)kNNodes * EMB / 4;
  const size_t i = (size_t)blockIdx.x * 256 + threadIdx.x;
  if (i >= allF4) return;
  const float4 v = ((const float4*)cur)[i];
  ushort4 h;
  h.x = f2bf(v.x); h.y = f2bf(v.y); h.z = f2bf(v.z); h.w = f2bf(v.w);
  ((ushort4*)cur16)[i] = h;
}

// ---------------------------------------------------------------------------
// CSR build (unchanged)
// ---------------------------------------------------------------------------
__global__ __launch_bounds__(256) void hist_rows(
    const int* __restrict__ rows, int* __restrict__ rowCnt)
{
  const int e = blockIdx.x * 256 + threadIdx.x;
  if (e < kNEdges) atomicAdd(&rowCnt[rows[e]], 1);
}

__global__ __launch_bounds__(256) void scan1(
    int* __restrict__ rowCnt, int* __restrict__ rowPtr,
    int* __restrict__ blockSums)
{
  __shared__ int wsum[4];
  const int tid  = threadIdx.x;
  const int lane = tid & 63;
  const int wid  = tid >> 6;
  const int i    = blockIdx.x * 256 + tid;
  const int cnt  = (i < kNNodes) ? rowCnt[i] : 0;
  int v = cnt;
#pragma unroll
  for (int off = 1; off < 64; off <<= 1) {
    const int n = __shfl_up(v, off, 64);
    if (lane >= off) v += n;
  }
  if (lane == 63) wsum[wid] = v;
  __syncthreads();
  if (tid == 0) {
    int s = 0;
#pragma unroll
    for (int w = 0; w < 4; ++w) { const int t = wsum[w]; wsum[w] = s; s += t; }
    blockSums[blockIdx.x] = s;
  }
  __syncthreads();
  if (i < kNNodes) {
    rowPtr[i] = wsum[wid] + v - cnt;
    rowCnt[i] = 0;
  }
}

__global__ __launch_bounds__(1024) void scan2(int* __restrict__ blockSums)
{
  __shared__ int wsum[16];
  const int tid  = threadIdx.x;
  const int lane = tid & 63;
  const int wid  = tid >> 6;
  const int cnt  = (tid < kScanB) ? blockSums[tid] : 0;
  int v = cnt;
#pragma unroll
  for (int off = 1; off < 64; off <<= 1) {
    const int n = __shfl_up(v, off, 64);
    if (lane >= off) v += n;
  }
  if (lane == 63) wsum[wid] = v;
  __syncthreads();
  if (tid == 0) {
    int s = 0;
#pragma unroll
    for (int w = 0; w < 16; ++w) { const int t = wsum[w]; wsum[w] = s; s += t; }
  }
  __syncthreads();
  if (tid < kScanB) blockSums[tid] = wsum[wid] + v - cnt;
}

__global__ __launch_bounds__(256) void scan3(
    int* __restrict__ rowPtr, const int* __restrict__ blockSums)
{
  const int i = blockIdx.x * 256 + threadIdx.x;
  if (i < kNNodes) rowPtr[i] += blockSums[blockIdx.x];
  if (i == 0) rowPtr[kNNodes] = kNEdges;
}

__global__ __launch_bounds__(256) void scatter_edges(
    const int* __restrict__ rows, const int* __restrict__ cols,
    const float* __restrict__ vals, const int* __restrict__ rowPtr,
    int* __restrict__ rowCnt, int2* __restrict__ edgeS)
{
  const int e = blockIdx.x * 256 + threadIdx.x;
  if (e >= kNEdges) return;
  const int r   = rows[e];
  const int idx = rowPtr[r] + atomicAdd(&rowCnt[r], 1);
  edgeS[idx] = make_int2(cols[e], __float_as_int(vals[e]));
}

// ---------------------------------------------------------------------------
// CSR SpMM, bf16 gather: one wave per row, lane = dim; 128 B/edge gather.
// ---------------------------------------------------------------------------
__global__ __launch_bounds__(256) void spmm_csr16(
    const unsigned short* __restrict__ cur16, const int* __restrict__ rowPtr,
    const int2* __restrict__ edgeS, float* __restrict__ nbuf)
{
  const int lane = threadIdx.x & 63;
  const int r = (blockIdx.x << 2) | (threadIdx.x >> 6);
  if (r >= kNNodes) return;
  const int start = __builtin_amdgcn_readfirstlane(rowPtr[r]);
  const int end   = __builtin_amdgcn_readfirstlane(rowPtr[r + 1]);
  float a0 = 0.f, a1 = 0.f, a2 = 0.f, a3 = 0.f;
  int e = start;
  for (; e + 4 <= end; e += 4) {
    const int2 cv0 = edgeS[e];
    const int2 cv1 = edgeS[e + 1];
    const int2 cv2 = edgeS[e + 2];
    const int2 cv3 = edgeS[e + 3];
    const unsigned short u0 = cur16[(size_t)cv0.x * EMB + lane];
    const unsigned short u1 = cur16[(size_t)cv1.x * EMB + lane];
    const unsigned short u2 = cur16[(size_t)cv2.x * EMB + lane];
    const unsigned short u3 = cur16[(size_t)cv3.x * EMB + lane];
    a0 = fmaf(__int_as_float(cv0.y), bf2f(u0), a0);
    a1 = fmaf(__int_as_float(cv1.y), bf2f(u1), a1);
    a2 = fmaf(__int_as_float(cv2.y), bf2f(u2), a2);
    a3 = fmaf(__int_as_float(cv3.y), bf2f(u3), a3);
  }
  for (; e < end; ++e) {
    const int2 cv = edgeS[e];
    a0 = fmaf(__int_as_float(cv.y), bf2f(cur16[(size_t)cv.x * EMB + lane]), a0);
  }
  nbuf[(size_t)r * EMB + lane] = (a0 + a1) + (a2 + a3);
}

// fp32-gather variant (fallback when ws can't hold cur16)
__global__ __launch_bounds__(256) void spmm_csr(
    const float* __restrict__ cur, const int* __restrict__ rowPtr,
    const int2* __restrict__ edgeS, float* __restrict__ nbuf)
{
  const int lane = threadIdx.x & 63;
  const int r = (blockIdx.x << 2) | (threadIdx.x >> 6);
  if (r >= kNNodes) return;
  const int start = __builtin_amdgcn_readfirstlane(rowPtr[r]);
  const int end   = __builtin_amdgcn_readfirstlane(rowPtr[r + 1]);
  float a0 = 0.f, a1 = 0.f, a2 = 0.f, a3 = 0.f;
  int e = start;
  for (; e + 4 <= end; e += 4) {
    const int2 cv0 = edgeS[e];
    const int2 cv1 = edgeS[e + 1];
    const int2 cv2 = edgeS[e + 2];
    const int2 cv3 = edgeS[e + 3];
    a0 = fmaf(__int_as_float(cv0.y), cur[(size_t)cv0.x * EMB + lane], a0);
    a1 = fmaf(__int_as_float(cv1.y), cur[(size_t)cv1.x * EMB + lane], a1);
    a2 = fmaf(__int_as_float(cv2.y), cur[(size_t)cv2.x * EMB + lane], a2);
    a3 = fmaf(__int_as_float(cv3.y), cur[(size_t)cv3.x * EMB + lane], a3);
  }
  for (; e < end; ++e) {
    const int2 cv = edgeS[e];
    a0 = fmaf(__int_as_float(cv.y), cur[(size_t)cv.x * EMB + lane], a0);
  }
  nbuf[(size_t)r * EMB + lane] = (a0 + a1) + (a2 + a3);
}

__global__ __launch_bounds__(256) void spmm_atomic(
    const float* __restrict__ cur, const int* __restrict__ rows,
    const int* __restrict__ cols, const float* __restrict__ vals,
    float* __restrict__ nbuf)
{
  const int lane = threadIdx.x & 63;
  int wv = (blockIdx.x << 2) | (threadIdx.x >> 6);
  wv = __builtin_amdgcn_readfirstlane(wv);
  int e0 = wv * kEPW;
  int e1 = e0 + kEPW;
  if (e1 > kNEdges) e1 = kNEdges;
  for (int e = e0; e < e1; ++e) {
    atomicAdd(nbuf + (size_t)rows[e] * EMB + lane,
              vals[e] * cur[(size_t)cols[e] * EMB + lane]);
  }
}

// ---------------------------------------------------------------------------
// Fused per-node transform — byte-identical to the R4 version (no bf16 path).
// ---------------------------------------------------------------------------
__global__ __launch_bounds__(256) void transform_inplace(
    float* __restrict__ cur, const float* __restrict__ nbuf,
    const float* __restrict__ W1, const float* __restrict__ b1,
    const float* __restrict__ W2, const float* __restrict__ b2)
{
  const int node = blockIdx.x * 256 + threadIdx.x;
  if (node >= kNNodes) return;

  const float4* __restrict__ xr  = (const float4*)(cur  + (size_t)node * EMB);
  const float4* __restrict__ nr  = (const float4*)(nbuf + (size_t)node * EMB);
  const float4* __restrict__ b1v = (const float4*)b1;
  const float4* __restrict__ b2v = (const float4*)b2;

  float4 acc1[16], acc2[16];
#pragma unroll
  for (int j = 0; j < 16; ++j) { acc1[j] = b1v[j]; acc2[j] = b2v[j]; }

#pragma unroll 2
  for (int k4 = 0; k4 < 16; ++k4) {
    const float4 xv = xr[k4];
    const float4 nv = nr[k4];
#pragma unroll
    for (int kk = 0; kk < 4; ++kk) {
      const int k = 4 * k4 + kk;
      const float xs = f4c(xv, kk);
      const float ns = f4c(nv, kk);
      const float4* __restrict__ w1r = (const float4*)(W1 + k * EMB);
      const float4* __restrict__ w2r = (const float4*)(W2 + k * EMB);
#pragma unroll
      for (int j = 0; j < 16; ++j) {
        acc1[j] = f4fma(xs, w1r[j], acc1[j]);
        acc2[j] = f4fma(ns, w2r[j], acc2[j]);
      }
    }
  }

#pragma unroll
  for (int k4 = 0; k4 < 16; ++k4) {
    const float4 xv = xr[k4];
    const float4 tv = acc2[k4];
#pragma unroll
    for (int kk = 0; kk < 4; ++kk) {
      const float ms = f4c(tv, kk) * f4c(xv, kk);
      const float4* __restrict__ w2r = (const float4*)(W2 + (4 * k4 + kk) * EMB);
#pragma unroll
      for (int j = 0; j < 16; ++j) acc1[j] = f4fma(ms, w2r[j], acc1[j]);
    }
  }

  float4* __restrict__ outp = (float4*)(cur + (size_t)node * EMB);
#pragma unroll
  for (int j = 0; j < 16; ++j) {
    float4 r;
    r.x = lrelu(acc1[j].x + acc2[j].x + b2v[j].x);
    r.y = lrelu(acc1[j].y + acc2[j].y + b2v[j].y);
    r.z = lrelu(acc1[j].z + acc2[j].z + b2v[j].z);
    r.w = lrelu(acc1[j].w + acc2[j].w + b2v[j].w);
    outp[j] = r;
  }
}

// ---------------------------------------------------------------------------
__global__ __launch_bounds__(256) void gather_out(
    const float* __restrict__ cur, const int* __restrict__ users,
    const int* __restrict__ pos, const int* __restrict__ neg,
    float* __restrict__ out, int layer)
{
  const int t    = blockIdx.x * 256 + threadIdx.x;
  const int lane = t & 63;
  const int rid  = t >> 6;
  if (rid >= 3 * kBatch) return;
  const int seg = rid / kBatch;
  const int b   = rid - seg * kBatch;
  int idx;
  if (seg == 0)      idx = users[b];
  else if (seg == 1) idx = pos[b] + kNUsers;
  else               idx = neg[b] + kNUsers;
  out[(size_t)rid * 256 + layer * EMB + lane] = cur[(size_t)idx * EMB + lane];
}

// ---------------------------------------------------------------------------
extern "C" void kernel_launch(void* const* d_in, const int* in_sizes, int n_in,
                              void* d_out, int out_size, void* d_ws, size_t ws_size,
                              hipStream_t stream) {
  const int*   users    = (const int*)d_in[0];
  const int*   pos      = (const int*)d_in[1];
  const int*   neg      = (const int*)d_in[2];
  const int*   rows     = (const int*)d_in[3];
  const int*   cols     = (const int*)d_in[4];
  const float* vals     = (const float*)d_in[5];
  const float* user_emb = (const float*)d_in[6];
  const float* item_emb = (const float*)d_in[7];
  const float* W1s      = (const float*)d_in[8];
  const float* b1s      = (const float*)d_in[9];
  const float* W2s      = (const float*)d_in[10];
  const float* b2s      = (const float*)d_in[11];
  float* out = (float*)d_out;

  const size_t nodeF = (size_t)kNNodes * EMB;
  float* cur  = (float*)d_ws;                               // 38.4 MB
  float* nbuf = cur + nodeF;                                // 38.4 MB
  int2*  edgeS     = (int2*)(nbuf + nodeF);                 // 38.4 MB
  int*   rowPtr    = (int*)(edgeS + kNEdges);               // 600 KB (+1)
  int*   rowCnt    = rowPtr + (kNNodes + 1);                // 600 KB
  int*   blockSums = rowCnt + kNNodes;                      // 2.3 KB
  unsigned short* cur16 = (unsigned short*)(blockSums + kScanB);  // 19.2 MB
  const size_t neededCsr = (size_t)((char*)cur16 - (char*)d_ws);
  const size_t needed16  = neededCsr + nodeF * sizeof(unsigned short);
  const bool useCsr = ws_size >= neededCsr;
  const bool use16  = useCsr && ws_size >= needed16;

  const dim3 blk(256);
  const int iblocks = (int)((nodeF / 4 + 255) / 256);       // 9375
  const int gblocks = (3 * kBatch * EMB + 255) / 256;       // 12288
  const int eblocks = (kNEdges + 255) / 256;                // 18750
  const int rblocks = (kNNodes + 3) / 4;                    // 37500
  const int tblocks = (kNNodes + 255) / 256;                // 586

  init_embed<<<iblocks, blk, 0, stream>>>(user_emb, item_emb, cur, cur16,
                                          use16 ? 1 : 0);

  if (useCsr) {
    hipMemsetAsync(rowCnt, 0, (size_t)kNNodes * sizeof(int), stream);
    hist_rows<<<eblocks, blk, 0, stream>>>(rows, rowCnt);
    scan1<<<kScanB, blk, 0, stream>>>(rowCnt, rowPtr, blockSums);
    scan2<<<1, 1024, 0, stream>>>(blockSums);
    scan3<<<kScanB, blk, 0, stream>>>(rowPtr, blockSums);
    scatter_edges<<<eblocks, blk, 0, stream>>>(rows, cols, vals, rowPtr,
                                               rowCnt, edgeS);
  }

  gather_out<<<gblocks, blk, 0, stream>>>(cur, users, pos, neg, out, 0);

  for (int L = 0; L < kLayers; ++L) {
    if (useCsr) {
      if (use16)
        spmm_csr16<<<rblocks, blk, 0, stream>>>(cur16, rowPtr, edgeS, nbuf);
      else
        spmm_csr<<<rblocks, blk, 0, stream>>>(cur, rowPtr, edgeS, nbuf);
    } else {
      hipMemsetAsync(nbuf, 0, nodeF * sizeof(float), stream);
      const int sblocks = (((kNEdges + kEPW - 1) / kEPW) + 3) / 4;
      spmm_atomic<<<sblocks, blk, 0, stream>>>(cur, rows, cols, vals, nbuf);
    }
    transform_inplace<<<tblocks, blk, 0, stream>>>(
        cur, nbuf, W1s + L * EMB * EMB, b1s + L * EMB,
        W2s + L * EMB * EMB, b2s + L * EMB);
    if (use16 && L + 1 < kLayers)
      refresh16<<<iblocks, blk, 0, stream>>>(cur, cur16);
    gather_out<<<gblocks, blk, 0, stream>>>(cur, users, pos, neg, out, L + 1);
  }
}